// Round 3
// baseline (219.847 us; speedup 1.0000x reference)
//
#include <hip/hip_runtime.h>

// VQ-VAE quantization, B-stationary MFMA formulation. MI355X gfx950.
// x: [131072, 64] f32; emb: [512, 64] f32.
// d_out: quantized_st [8388608] | loss [1] | perplexity [1].
//
// Each wave owns 128 codes: B_h/B_m frags in VGPRs (persistent), B_l in LDS in
// fragment order (conflict-free ds_read_b128). K-loop over row-tiles has no
// staging; 1 barrier/tile for cross-wave argmin. Score numerics bit-identical
// to R2 (same split, same 12-MFMA order, same sum trees) -> absmax 0.

#define D      64
#define M      512
#define N_VEC  131072
#define N_ELEM 8388608
#define TPB    8        // row-tiles (of 16 rows) per block

typedef __attribute__((ext_vector_type(8))) short short8;
typedef __attribute__((ext_vector_type(4))) float f32x4;

// ws byte layout: [0,4) loss f32 | [4,2052) counts u32[512] | [4096,6144) bnorm f32[512]
// | [8192, 8192+196608) bf16 planes in FRAGMENT order:
//   plane p at p*32768 shorts; element (ct,s,lane,j) at ((ct*2+s)*64+lane)*8+j
//   holding split_p(emb[ct*16 + (lane&15)][s*32 + (lane>>4)*8 + j]).

static __device__ __forceinline__ unsigned short f2bf(float f) {
    unsigned u = __float_as_uint(f);
    return (unsigned short)((u + 0x7FFFu + ((u >> 16) & 1u)) >> 16);  // RNE
}
static __device__ __forceinline__ float bf2f(unsigned short h) {
    return __uint_as_float(((unsigned)h) << 16);
}

__global__ __launch_bounds__(256)
void vq_prep(const float* __restrict__ emb, float* __restrict__ bnorm,
             unsigned short* __restrict__ planes, unsigned int* __restrict__ counts,
             float* __restrict__ loss_sum) {
    const int c = blockIdx.x * 256 + threadIdx.x;   // grid 2 x 256 = 512 codes
    counts[c] = 0u;                                  // zero ws accumulators (re-poisoned每 call)
    if (c == 0) *loss_sum = 0.f;
    const float* e = emb + c * D;
    float s0 = 0.f, s1 = 0.f, s2 = 0.f, s3 = 0.f;   // same tree as R1/R2 (bit-exact)
    for (int k = 0; k < D; k += 4) {
        float e0 = e[k], e1 = e[k + 1], e2 = e[k + 2], e3 = e[k + 3];
        s0 = fmaf(e0, e0, s0); s1 = fmaf(e1, e1, s1);
        s2 = fmaf(e2, e2, s2); s3 = fmaf(e3, e3, s3);
    }
    bnorm[c] = (s0 + s1) + (s2 + s3);
    const int ct = c >> 4, col = c & 15;
    for (int k = 0; k < D; ++k) {
        float v = e[k];
        unsigned short hh = f2bf(v);
        float r1 = v - bf2f(hh);
        unsigned short mm = f2bf(r1);
        float r2 = r1 - bf2f(mm);
        unsigned short ll = f2bf(r2);
        const int s = k >> 5, q = (k >> 3) & 3, j = k & 7;
        const int lane = q * 16 + col;
        const int base = ((ct * 2 + s) * 64 + lane) * 8 + j;
        planes[0 * 32768 + base] = hh;
        planes[1 * 32768 + base] = mm;
        planes[2 * 32768 + base] = ll;
    }
}

__global__ __launch_bounds__(256, 2)   // cap VGPR at 256 -> 2 waves/SIMD
void vq_main(const float* __restrict__ x, const float* __restrict__ emb,
             const float* __restrict__ bnorm, const unsigned short* __restrict__ planes,
             float* __restrict__ out, float* __restrict__ loss_sum,
             unsigned int* __restrict__ counts) {
    __shared__ __align__(16) short sBl[32768];      // 64 KB: 4 waves x 8ct x 2s x 64 lanes x 8
    __shared__ float sBest[2][4][16];
    __shared__ int   sBidx[2][4][16];
    __shared__ float sRed[4];

    const int tid = threadIdx.x;
    const int w = tid >> 6, lane = tid & 63;
    const int q = lane >> 4, col = lane & 15;
    const int rowBase0 = blockIdx.x * (TPB * 16);

    // ---- B: h/m frags -> registers (persistent), l -> LDS in frag order ----
    short8 Bh[8][2], Bm[8][2];
    float Bn[8];
#pragma unroll
    for (int t = 0; t < 8; ++t) {
        const int ct = w * 8 + t;
        Bn[t] = bnorm[ct * 16 + col];
#pragma unroll
        for (int s = 0; s < 2; ++s) {
            const int base = ((ct * 2 + s) * 64 + lane) * 8;
            Bh[t][s] = *(const short8*)(planes + 0 * 32768 + base);
            Bm[t][s] = *(const short8*)(planes + 1 * 32768 + base);
            short8 bl = *(const short8*)(planes + 2 * 32768 + base);
            *(short8*)&sBl[(w * 16 + t * 2 + s) * 512 + lane * 8] = bl;  // own region only
        }
    }

    float lacc = 0.f;

    // preload tile 0's x (A-frag pattern: lane holds row=col, k = q*8+j, s in {0,1})
    const float* xp0 = x + (size_t)(rowBase0 + col) * D + q * 8;
    float4 xa = *(const float4*)(xp0);
    float4 xb = *(const float4*)(xp0 + 4);
    float4 xc = *(const float4*)(xp0 + 32);
    float4 xd = *(const float4*)(xp0 + 36);

#pragma unroll 1
    for (int it = 0; it < TPB; ++it) {
        // ---- ||x_row||^2 via butterfly, reproducing R1's exact tree ----
        float pa = (xa.x * xa.x + xa.y * xa.y) + (xa.z * xa.z + xa.w * xa.w);
        float pb = (xb.x * xb.x + xb.y * xb.y) + (xb.z * xb.z + xb.w * xb.w);
        float pc = (xc.x * xc.x + xc.y * xc.y) + (xc.z * xc.z + xc.w * xc.w);
        float pd = (xd.x * xd.x + xd.y * xd.y) + (xd.z * xd.z + xd.w * xd.w);
        float u = pa + pb, vv = pc + pd;
        u  += __shfl_xor(u, 16, 64);  u  += __shfl_xor(u, 32, 64);   // q0+q1 (commutative)
        vv += __shfl_xor(vv, 16, 64); vv += __shfl_xor(vv, 32, 64);  // q2+q3
        const float An = u + vv;   // (q0+q1)+(q2+q3): norm of row (lane&15)
        float Ar[4];
#pragma unroll
        for (int r = 0; r < 4; ++r) Ar[r] = __shfl(An, q * 4 + r, 64);

        // ---- split x -> A frags ----
        float f[16] = {xa.x, xa.y, xa.z, xa.w, xb.x, xb.y, xb.z, xb.w,
                       xc.x, xc.y, xc.z, xc.w, xd.x, xd.y, xd.z, xd.w};
        short8 Ah0, Am0, Al0, Ah1, Am1, Al1;
#pragma unroll
        for (int j = 0; j < 8; ++j) {
            {
                float v0 = f[j];
                unsigned short hh = f2bf(v0); float r1 = v0 - bf2f(hh);
                unsigned short mm = f2bf(r1); float r2 = r1 - bf2f(mm);
                Ah0[j] = (short)hh; Am0[j] = (short)mm; Al0[j] = (short)f2bf(r2);
            }
            {
                float v0 = f[8 + j];
                unsigned short hh = f2bf(v0); float r1 = v0 - bf2f(hh);
                unsigned short mm = f2bf(r1); float r2 = r1 - bf2f(mm);
                Ah1[j] = (short)hh; Am1[j] = (short)mm; Al1[j] = (short)f2bf(r2);
            }
        }

        // prefetch next tile's x (lands during MFMA phase)
        if (it + 1 < TPB) {
            const float* xp = x + (size_t)(rowBase0 + (it + 1) * 16 + col) * D + q * 8;
            xa = *(const float4*)(xp);
            xb = *(const float4*)(xp + 4);
            xc = *(const float4*)(xp + 32);
            xd = *(const float4*)(xp + 36);
        }

        // ---- 8 col-tiles x 12 MFMA, same order/grouping as R2 (bit-exact) ----
        float best[4] = {3.4e38f, 3.4e38f, 3.4e38f, 3.4e38f};
        int   bidx[4] = {0, 0, 0, 0};
#pragma unroll
        for (int t = 0; t < 8; ++t) {
            short8 Bl0 = *(const short8*)&sBl[(w * 16 + t * 2 + 0) * 512 + lane * 8];
            short8 Bl1 = *(const short8*)&sBl[(w * 16 + t * 2 + 1) * 512 + lane * 8];
            f32x4 a1 = {0.f, 0.f, 0.f, 0.f}, a2 = a1, a3 = a1;
            a1 = __builtin_amdgcn_mfma_f32_16x16x32_bf16(Ah0, Bh[t][0], a1, 0, 0, 0);
            a1 = __builtin_amdgcn_mfma_f32_16x16x32_bf16(Ah1, Bh[t][1], a1, 0, 0, 0);
            a2 = __builtin_amdgcn_mfma_f32_16x16x32_bf16(Ah0, Bm[t][0], a2, 0, 0, 0);
            a2 = __builtin_amdgcn_mfma_f32_16x16x32_bf16(Ah1, Bm[t][1], a2, 0, 0, 0);
            a2 = __builtin_amdgcn_mfma_f32_16x16x32_bf16(Am0, Bh[t][0], a2, 0, 0, 0);
            a2 = __builtin_amdgcn_mfma_f32_16x16x32_bf16(Am1, Bh[t][1], a2, 0, 0, 0);
            a3 = __builtin_amdgcn_mfma_f32_16x16x32_bf16(Am0, Bm[t][0], a3, 0, 0, 0);
            a3 = __builtin_amdgcn_mfma_f32_16x16x32_bf16(Am1, Bm[t][1], a3, 0, 0, 0);
            a3 = __builtin_amdgcn_mfma_f32_16x16x32_bf16(Ah0, Bl0, a3, 0, 0, 0);
            a3 = __builtin_amdgcn_mfma_f32_16x16x32_bf16(Ah1, Bl1, a3, 0, 0, 0);
            a3 = __builtin_amdgcn_mfma_f32_16x16x32_bf16(Al0, Bh[t][0], a3, 0, 0, 0);
            a3 = __builtin_amdgcn_mfma_f32_16x16x32_bf16(Al1, Bh[t][1], a3, 0, 0, 0);

            const int code = w * 128 + t * 16 + col;
#pragma unroll
            for (int r = 0; r < 4; ++r) {
                float dot = a1[r] + (a2[r] + a3[r]);
                float score = fmaf(-2.0f, dot, Ar[r]) + Bn[t];
                if (score < best[r]) { best[r] = score; bidx[r] = code; }
            }
        }

        // ---- intra-wave argmin across the 16 col-lanes ----
#pragma unroll
        for (int off = 1; off < 16; off <<= 1) {
#pragma unroll
            for (int r = 0; r < 4; ++r) {
                float ob = __shfl_xor(best[r], off, 64);
                int   oi = __shfl_xor(bidx[r], off, 64);
                if (ob < best[r] || (ob == best[r] && oi < bidx[r])) { best[r] = ob; bidx[r] = oi; }
            }
        }
        const int buf = it & 1;
        if (col == 0) {
#pragma unroll
            for (int r = 0; r < 4; ++r) {
                sBest[buf][w][q * 4 + r] = best[r];
                sBidx[buf][w][q * 4 + r] = bidx[r];
            }
        }
        __syncthreads();

        // ---- epilogue: cross-wave reduce (redundant per-thread), gather, write ----
        {
            const int v = tid >> 4, seg = tid & 15;
            float b = sBest[buf][0][v];
            int   ci = sBidx[buf][0][v];
#pragma unroll
            for (int w2 = 1; w2 < 4; ++w2) {
                float ob = sBest[buf][w2][v];
                int   oi = sBidx[buf][w2][v];
                if (ob < b || (ob == b && oi < ci)) { b = ob; ci = oi; }
            }
            const size_t grow = (size_t)(rowBase0 + it * 16 + v) * D + seg * 4;
            float4 xv = *(const float4*)(x + grow);                  // L1-hot
            float4 qv = *(const float4*)(emb + (size_t)ci * D + seg * 4);
            float e0 = xv.x - qv.x, e1 = xv.y - qv.y, e2 = xv.z - qv.z, e3 = xv.w - qv.w;
            lacc = fmaf(e0, e0, lacc); lacc = fmaf(e1, e1, lacc);
            lacc = fmaf(e2, e2, lacc); lacc = fmaf(e3, e3, lacc);
            float4 o;  // out = fl(x + fl(q - x)) == fl(x - fl(x - q)) bit-exactly
            o.x = xv.x - e0; o.y = xv.y - e1; o.z = xv.z - e2; o.w = xv.w - e3;
            *(float4*)(out + grow) = o;
            if (seg == 0) atomicAdd(&counts[ci], 1u);
        }
    }

    // ---- loss reduction ----
#pragma unroll
    for (int off = 32; off > 0; off >>= 1) lacc += __shfl_down(lacc, off, 64);
    if (lane == 0) sRed[w] = lacc;
    __syncthreads();
    if (tid == 0) atomicAdd(loss_sum, (sRed[0] + sRed[1]) + (sRed[2] + sRed[3]));
}

__global__ __launch_bounds__(512)
void vq_final(const unsigned int* __restrict__ counts,
              const float* __restrict__ loss_sum, float* __restrict__ out) {
    __shared__ float sRed[8];
    const int t = threadIdx.x;  // one per bin
    const float p = (float)counts[t] * (1.0f / 131072.0f);
    float term = p * logf(p + 1e-10f);
#pragma unroll
    for (int off = 32; off > 0; off >>= 1) term += __shfl_down(term, off, 64);
    if ((t & 63) == 0) sRed[t >> 6] = term;
    __syncthreads();
    if (t == 0) {
        float s = 0.f;
#pragma unroll
        for (int w = 0; w < 8; ++w) s += sRed[w];
        out[N_ELEM]     = 0.25f * (loss_sum[0] * (1.0f / 8388608.0f));
        out[N_ELEM + 1] = expf(-s);
    }
}

extern "C" void kernel_launch(void* const* d_in, const int* in_sizes, int n_in,
                              void* d_out, int out_size, void* d_ws, size_t ws_size,
                              hipStream_t stream) {
    (void)in_sizes; (void)n_in; (void)out_size; (void)ws_size;
    const float* x   = (const float*)d_in[0];
    const float* emb = (const float*)d_in[1];
    float* out = (float*)d_out;

    float*          loss  = (float*)d_ws;
    unsigned int*   cnts  = (unsigned int*)((char*)d_ws + 4);
    float*          bnorm = (float*)((char*)d_ws + 4096);
    unsigned short* plns  = (unsigned short*)((char*)d_ws + 8192);

    vq_prep<<<dim3(2), dim3(256), 0, stream>>>(emb, bnorm, plns, cnts, loss);
    vq_main<<<dim3(N_VEC / (TPB * 16)), dim3(256), 0, stream>>>(x, emb, bnorm, plns, out, loss, cnts);
    vq_final<<<dim3(1), dim3(512), 0, stream>>>(cnts, loss, out);
}